// Round 11
// baseline (262.078 us; speedup 1.0000x reference)
//
#include <hip/hip_runtime.h>
#include <hip/hip_bf16.h>

#define S_LEN 2048
#define NHEAD 16
#define HDIM 64
#define HID 1024

typedef __attribute__((ext_vector_type(8))) short bf16x8;
typedef __attribute__((ext_vector_type(4))) float f32x4;
typedef __attribute__((ext_vector_type(4))) unsigned int u32x4;
typedef __attribute__((ext_vector_type(2))) unsigned int u32x2;

__device__ __forceinline__ unsigned short f2bf(float x) {
    unsigned int u = __builtin_bit_cast(unsigned int, x);
    u = (u + 0x7fffu + ((u >> 16) & 1u)) >> 16;
    return (unsigned short)u;
}
__device__ __forceinline__ float bf2f(unsigned short s) {
    unsigned int u = ((unsigned int)s) << 16;
    return __builtin_bit_cast(float, u);
}
__device__ __forceinline__ unsigned cvtpk_bf16(float lo, float hi) {
    unsigned r;
    asm("v_cvt_pk_bf16_f32 %0, %1, %2" : "=v"(r) : "v"(lo), "v"(hi));
    return r;
}
__device__ __forceinline__ void gload16(const short* g, short* l) {
    __builtin_amdgcn_global_load_lds(
        (const __attribute__((address_space(1))) unsigned int*)g,
        (__attribute__((address_space(3))) unsigned int*)l, 16, 0, 0);
}
__device__ __forceinline__ bf16x8 negbf8(bf16x8 v) {
    u32x4 u = __builtin_bit_cast(u32x4, v);
    #pragma unroll
    for (int e = 0; e < 4; e++) u[e] ^= 0x80008000u;
    return __builtin_bit_cast(bf16x8, u);
}

// scale folded into Q: scores arrive as flow*log2(e) -> softmax via exp2
#define QSCALE 0.1803368801111168f   // 0.125 * log2(e)

// ---------------- prep: f32 -> bf16 convert (vectorized) ----------------
__global__ void cvt_kernel(const float* __restrict__ src, short* __restrict__ dst, int n4) {
    int i = blockIdx.x * blockDim.x + threadIdx.x;
    if (i < n4) {
        float4 v = reinterpret_cast<const float4*>(src)[i];
        short4 o;
        o.x = (short)f2bf(v.x); o.y = (short)f2bf(v.y);
        o.z = (short)f2bf(v.z); o.w = (short)f2bf(v.w);
        reinterpret_cast<short4*>(dst)[i] = o;
    }
}

// ------------- prep: tiled transpose f32 [R][C] -> bf16 [C][R] ----------
__global__ void transpose_bf16(const float* __restrict__ src, short* __restrict__ dst,
                               int R, int C) {
    __shared__ float tile[32][33];
    int bx = blockIdx.x * 32;
    int by = blockIdx.y * 32;
    int tx = threadIdx.x, ty = threadIdx.y;  // 32 x 8
    #pragma unroll
    for (int i = ty; i < 32; i += 8)
        tile[i][tx] = src[(size_t)(by + i) * C + bx + tx];
    __syncthreads();
    #pragma unroll
    for (int i = ty; i < 32; i += 8)
        dst[(size_t)(bx + i) * R + by + tx] = (short)f2bf(tile[tx][i]);
}

// ----- per-head V transpose: Vb[b*2048+s][h*64+dv] -> VT[(b*16+h)*64+dv][s]
__global__ void vtrans_kernel(const short* __restrict__ Vb, short* __restrict__ VT) {
    __shared__ short tile[32][34];
    int s0 = blockIdx.x * 32;
    int dv0 = blockIdx.y * 32;
    int bh = blockIdx.z;
    int b = bh >> 4, h = bh & 15;
    int tx = threadIdx.x, ty = threadIdx.y;  // 32 x 8
    #pragma unroll
    for (int i = ty; i < 32; i += 8)
        tile[i][tx] = Vb[(size_t)(b * S_LEN + s0 + i) * HID + h * HDIM + dv0 + tx];
    __syncthreads();
    #pragma unroll
    for (int i = ty; i < 32; i += 8)
        VT[(size_t)(bh * HDIM + dv0 + i) * S_LEN + s0 + tx] = tile[tx][i];
}

// ---------------- QKV GEMM: [4096,1024] @ [1024,3072] -------------------
__global__ __launch_bounds__(256, 2)
void gemm_qkv(const short* __restrict__ xb, const short* __restrict__ WT,
              const float* __restrict__ bq, const float* __restrict__ bk,
              const float* __restrict__ bv,
              short* __restrict__ Qb, short* __restrict__ Kb, short* __restrict__ Vb) {
    __shared__ short Al[128 * 32];
    __shared__ short Bl[128 * 32];
    int mb = blockIdx.x, nb = blockIdx.y;
    int tid = threadIdx.x;
    int wave = tid >> 6, lane = tid & 63;
    int wm = wave >> 1, wn = wave & 1;
    int lr = lane & 15, lg = lane >> 4;

    int r = tid >> 2;
    int c = tid & 3;
    int sc = (c ^ (r & 3)) * 8;
    int dst0 = tid * 8;
    int dst1 = (tid + 256) * 8;
    const short* a0 = xb + (size_t)(mb * 128 + r) * 1024 + sc;
    const short* a1 = a0 + (size_t)64 * 1024;
    const short* b0 = WT + (size_t)(nb * 128 + r) * 1024 + sc;
    const short* b1 = b0 + (size_t)64 * 1024;
    int fsw = (lg ^ (lr & 3)) * 8;

    f32x4 acc[4][4] = {};

    for (int ks = 0; ks < 32; ++ks) {
        __syncthreads();
        gload16(a0 + ks * 32, &Al[dst0]);
        gload16(a1 + ks * 32, &Al[dst1]);
        gload16(b0 + ks * 32, &Bl[dst0]);
        gload16(b1 + ks * 32, &Bl[dst1]);
        __syncthreads();
        bf16x8 af[4], bfr[4];
        #pragma unroll
        for (int t = 0; t < 4; t++)
            af[t] = *(bf16x8*)&Al[(wm * 64 + t * 16 + lr) * 32 + fsw];
        #pragma unroll
        for (int t = 0; t < 4; t++)
            bfr[t] = *(bf16x8*)&Bl[(wn * 64 + t * 16 + lr) * 32 + fsw];
        #pragma unroll
        for (int i = 0; i < 4; i++)
            #pragma unroll
            for (int jn = 0; jn < 4; jn++)
                acc[i][jn] = __builtin_amdgcn_mfma_f32_16x16x32_bf16(af[i], bfr[jn], acc[i][jn], 0, 0, 0);
    }

    #pragma unroll
    for (int jn = 0; jn < 4; jn++) {
        int n = nb * 128 + wn * 64 + jn * 16 + lr;
        int which = n >> 10;
        int n1 = n & 1023;
        const float* bias = (which == 0) ? bq : (which == 1) ? bk : bv;
        short* out = (which == 0) ? Qb : (which == 1) ? Kb : Vb;
        float scale = (which == 0) ? QSCALE : 1.0f;
        float bv_ = bias[n1];
        #pragma unroll
        for (int i = 0; i < 4; i++) {
            #pragma unroll
            for (int j = 0; j < 4; j++) {
                int mm = mb * 128 + wm * 64 + i * 16 + lg * 4 + j;
                out[(size_t)mm * 1024 + n1] = (short)f2bf((acc[i][jn][j] + bv_) * scale);
            }
        }
    }
}

// ---------------- flash attention with antisymmetric flow ---------------
// 128 q-rows/block (grid 512): each wave owns TWO 16-row q-groups, so every
// Kt/Qt/Vt LDS fragment read feeds 2x the MFMAs (tile-read amortization).
// Staging via global_load_lds w=16: pre-swizzled per-lane SOURCE + linear
// dest + swizzled reads (T2). Log2-domain softmax, negated wave-side Kf,
// defer-max (T13), Pl LDS P-path (known good).
__global__ __launch_bounds__(256, 4)
void attn_kernel(const short* __restrict__ Qb, const short* __restrict__ Kb,
                 const short* __restrict__ VT, short* __restrict__ Fb) {
    __shared__ short Kt[64 * 64];
    __shared__ short Qt[64 * 64];
    __shared__ short Vt[64 * 64];
    __shared__ short Pl[128 * 64];   // P rows: (wave*2+g)*16 + lr

    int bid = blockIdx.x;
    int qb = bid & 15;               // 128-row q block
    int bh = bid >> 4;
    int b = bh >> 4, h = bh & 15;
    int tid = threadIdx.x;
    int wave = tid >> 6, lane = tid & 63;
    int lr = lane & 15, lg = lane >> 4;

    // wave-side fragments for the two q-groups; Kf negated once
    bf16x8 Qf[2][2], Kf[2][2];
    #pragma unroll
    for (int g = 0; g < 2; g++) {
        size_t rowbase = ((size_t)(b * S_LEN + qb * 128 + g * 64 + wave * 16 + lr)) * HID + h * HDIM;
        #pragma unroll
        for (int cc = 0; cc < 2; cc++) {
            Qf[g][cc] = *(const bf16x8*)(Qb + rowbase + cc * 32 + lg * 8);
            Kf[g][cc] = negbf8(*(const bf16x8*)(Kb + rowbase + cc * 32 + lg * 8));
        }
    }

    // staging: thread (r0=tid>>3, c=tid&7) stages rows r0, r0+32 of K,Q,V
    int r0 = tid >> 3;
    int c = tid & 7;
    int sc8 = (c ^ (r0 & 7)) * 8;    // swizzled SOURCE chunk ((r0+32)&7 == r0&7)
    const short* kp = Kb + (size_t)(b * S_LEN + r0) * HID + h * HDIM + sc8;
    const short* qp = Qb + (size_t)(b * S_LEN + r0) * HID + h * HDIM + sc8;
    const short* vp = VT + (size_t)bh * HDIM * S_LEN + (size_t)r0 * S_LEN + sc8;
    short* dK0 = &Kt[tid * 8]; short* dK1 = &Kt[(tid + 256) * 8];
    short* dQ0 = &Qt[tid * 8]; short* dQ1 = &Qt[(tid + 256) * 8];
    short* dV0 = &Vt[tid * 8]; short* dV1 = &Vt[(tid + 256) * 8];

    f32x4 O0[4] = {}, O1[4] = {};
    float m0 = -1e30f, l0 = 0.f, m1 = -1e30f, l1 = 0.f;
    int prow0 = ((wave * 2 + 0) * 16 + lr) * 64;
    int prow1 = ((wave * 2 + 1) * 16 + lr) * 64;

    for (int kt = 0; kt < 32; ++kt) {
        __syncthreads();
        gload16(kp, dK0); gload16(kp + 32 * HID, dK1);
        gload16(qp, dQ0); gload16(qp + 32 * HID, dQ1);
        gload16(vp, dV0); gload16(vp + 32 * S_LEN, dV1);
        kp += 64 * HID; qp += 64 * HID; vp += 64;
        __syncthreads();

        // shared kf/qf reads feed both q-groups (4 MFMAs per read pair)
        f32x4 S0[4] = {}, S1[4] = {};
        __builtin_amdgcn_s_setprio(1);
        #pragma unroll
        for (int t = 0; t < 4; t++) {
            #pragma unroll
            for (int c2 = 0; c2 < 2; c2++) {
                int fo = (t * 16 + lr) * 64 + (((4 * c2 + lg) ^ (lr & 7)) * 8);
                bf16x8 kf = *(bf16x8*)&Kt[fo];
                bf16x8 qf = *(bf16x8*)&Qt[fo];
                S0[t] = __builtin_amdgcn_mfma_f32_16x16x32_bf16(kf, Qf[0][c2], S0[t], 0, 0, 0);
                S0[t] = __builtin_amdgcn_mfma_f32_16x16x32_bf16(qf, Kf[0][c2], S0[t], 0, 0, 0);
                S1[t] = __builtin_amdgcn_mfma_f32_16x16x32_bf16(kf, Qf[1][c2], S1[t], 0, 0, 0);
                S1[t] = __builtin_amdgcn_mfma_f32_16x16x32_bf16(qf, Kf[1][c2], S1[t], 0, 0, 0);
            }
        }
        __builtin_amdgcn_s_setprio(0);

        float pm0 = -1e30f, pm1 = -1e30f;
        #pragma unroll
        for (int t = 0; t < 4; t++)
            #pragma unroll
            for (int j = 0; j < 4; j++) {
                pm0 = fmaxf(pm0, S0[t][j]);
                pm1 = fmaxf(pm1, S1[t][j]);
            }
        pm0 = fmaxf(pm0, __shfl_xor(pm0, 16));
        pm0 = fmaxf(pm0, __shfl_xor(pm0, 32));
        pm1 = fmaxf(pm1, __shfl_xor(pm1, 16));
        pm1 = fmaxf(pm1, __shfl_xor(pm1, 32));

        // defer-max (T13), both groups share the branch
        if (__any((pm0 > m0 + 8.f) || (pm1 > m1 + 8.f))) {
            float mn0 = fmaxf(m0, pm0), mn1 = fmaxf(m1, pm1);
            float al0 = exp2f(m0 - mn0), al1 = exp2f(m1 - mn1);
            m0 = mn0; m1 = mn1;
            l0 *= al0; l1 *= al1;
            float a0[4], a1[4];
            #pragma unroll
            for (int j = 0; j < 4; j++) {
                a0[j] = __shfl(al0, lg * 4 + j);
                a1[j] = __shfl(al1, lg * 4 + j);
            }
            #pragma unroll
            for (int dvt = 0; dvt < 4; dvt++)
                #pragma unroll
                for (int j = 0; j < 4; j++) {
                    O0[dvt][j] *= a0[j];
                    O1[dvt][j] *= a1[j];
                }
        }

        // P = exp2(S-m) -> Pl (paired b64 writes), row sums
        float rs0 = 0.f, rs1 = 0.f;
        #pragma unroll
        for (int t = 0; t < 4; t++) {
            float p0 = exp2f(S0[t][0] - m0), p1 = exp2f(S0[t][1] - m0);
            float p2 = exp2f(S0[t][2] - m0), p3 = exp2f(S0[t][3] - m0);
            rs0 += (p0 + p1) + (p2 + p3);
            u32x2 pw;
            pw[0] = cvtpk_bf16(p0, p1);
            pw[1] = cvtpk_bf16(p2, p3);
            int po = prow0 + (((2 * t + (lg >> 1)) ^ (lr & 7)) * 8) + (lg & 1) * 4;
            *(u32x2*)&Pl[po] = pw;
        }
        #pragma unroll
        for (int t = 0; t < 4; t++) {
            float p0 = exp2f(S1[t][0] - m1), p1 = exp2f(S1[t][1] - m1);
            float p2 = exp2f(S1[t][2] - m1), p3 = exp2f(S1[t][3] - m1);
            rs1 += (p0 + p1) + (p2 + p3);
            u32x2 pw;
            pw[0] = cvtpk_bf16(p0, p1);
            pw[1] = cvtpk_bf16(p2, p3);
            int po = prow1 + (((2 * t + (lg >> 1)) ^ (lr & 7)) * 8) + (lg & 1) * 4;
            *(u32x2*)&Pl[po] = pw;
        }
        rs0 += __shfl_xor(rs0, 16);
        rs0 += __shfl_xor(rs0, 32);
        rs1 += __shfl_xor(rs1, 16);
        rs1 += __shfl_xor(rs1, 32);
        l0 += rs0; l1 += rs1;

        // PV: shared vf reads feed both groups
        __builtin_amdgcn_s_setprio(1);
        #pragma unroll
        for (int c2 = 0; c2 < 2; c2++) {
            int pc = ((4 * c2 + lg) ^ (lr & 7)) * 8;
            bf16x8 pf0 = *(bf16x8*)&Pl[prow0 + pc];
            bf16x8 pf1 = *(bf16x8*)&Pl[prow1 + pc];
            #pragma unroll
            for (int dvt = 0; dvt < 4; dvt++) {
                bf16x8 vf = *(bf16x8*)&Vt[(dvt * 16 + lr) * 64 + pc];
                O0[dvt] = __builtin_amdgcn_mfma_f32_16x16x32_bf16(pf0, vf, O0[dvt], 0, 0, 0);
                O1[dvt] = __builtin_amdgcn_mfma_f32_16x16x32_bf16(pf1, vf, O1[dvt], 0, 0, 0);
            }
        }
        __builtin_amdgcn_s_setprio(0);
    }

    float li0[4], li1[4];
    float v0 = 1.f / l0, v1 = 1.f / l1;
    #pragma unroll
    for (int j = 0; j < 4; j++) {
        li0[j] = __shfl(v0, lg * 4 + j);
        li1[j] = __shfl(v1, lg * 4 + j);
    }
    #pragma unroll
    for (int dvt = 0; dvt < 4; dvt++) {
        #pragma unroll
        for (int j = 0; j < 4; j++) {
            int dv = dvt * 16 + lr;
            int q0 = qb * 128 + wave * 16 + lg * 4 + j;
            int q1 = q0 + 64;
            Fb[((size_t)(b * S_LEN + q0)) * HID + h * HDIM + dv] = (short)f2bf(O0[dvt][j] * li0[j]);
            Fb[((size_t)(b * S_LEN + q1)) * HID + h * HDIM + dv] = (short)f2bf(O1[dvt][j] * li1[j]);
        }
    }
}

// ------- gate GEMM (K=2048 over [xb | flowed]) + sigmoid + residual -----
__global__ __launch_bounds__(256, 2)
void gemm_gate(const short* __restrict__ xb, const short* __restrict__ fb,
               const short* __restrict__ WgT, const float* __restrict__ bg,
               const float* __restrict__ x, float* __restrict__ y) {
    __shared__ short Al[128 * 32];
    __shared__ short Bl[128 * 32];
    int mb = blockIdx.x, nb = blockIdx.y;
    int tid = threadIdx.x;
    int wave = tid >> 6, lane = tid & 63;
    int wm = wave >> 1, wn = wave & 1;
    int lr = lane & 15, lg = lane >> 4;

    int r = tid >> 2;
    int c = tid & 3;
    int sc = (c ^ (r & 3)) * 8;
    int dst0 = tid * 8;
    int dst1 = (tid + 256) * 8;
    size_t arow0 = (size_t)(mb * 128 + r) * 1024 + sc;
    size_t arow1 = arow0 + (size_t)64 * 1024;
    const short* b0 = WgT + (size_t)(nb * 128 + r) * 2048 + sc;
    const short* b1 = b0 + (size_t)64 * 2048;
    int fsw = (lg ^ (lr & 3)) * 8;

    f32x4 acc[4][4] = {};

    for (int ks = 0; ks < 64; ++ks) {
        int kg = ks * 32;
        const short* A = (kg < 1024) ? (xb + kg) : (fb + (kg - 1024));
        __syncthreads();
        gload16(A + arow0, &Al[dst0]);
        gload16(A + arow1, &Al[dst1]);
        gload16(b0 + kg, &Bl[dst0]);
        gload16(b1 + kg, &Bl[dst1]);
        __syncthreads();
        bf16x8 af[4], bfr[4];
        #pragma unroll
        for (int t = 0; t < 4; t++)
            af[t] = *(bf16x8*)&Al[(wm * 64 + t * 16 + lr) * 32 + fsw];
        #pragma unroll
        for (int t = 0; t < 4; t++)
            bfr[t] = *(bf16x8*)&Bl[(wn * 64 + t * 16 + lr) * 32 + fsw];
        #pragma unroll
        for (int i = 0; i < 4; i++)
            #pragma unroll
            for (int jn = 0; jn < 4; jn++)
                acc[i][jn] = __builtin_amdgcn_mfma_f32_16x16x32_bf16(af[i], bfr[jn], acc[i][jn], 0, 0, 0);
    }

    #pragma unroll
    for (int jn = 0; jn < 4; jn++) {
        int n = nb * 128 + wn * 64 + jn * 16 + lr;
        float bgv = bg[n];
        #pragma unroll
        for (int i = 0; i < 4; i++) {
            #pragma unroll
            for (int j = 0; j < 4; j++) {
                int mm = mb * 128 + wm * 64 + i * 16 + lg * 4 + j;
                size_t idx = (size_t)mm * 1024 + n;
                float z = acc[i][jn][j] + bgv;
                float gate = 1.f / (1.f + __expf(-z));
                float fv = bf2f((unsigned short)fb[idx]);
                y[idx] = x[idx] + gate * fv;
            }
        }
    }
}

// ---------------- row LayerNorm in place (fp32 -> fp32) ----------------
__global__ __launch_bounds__(256)
void ln_kernel(float* __restrict__ y, const float* __restrict__ gamma,
               const float* __restrict__ beta) {
    int row = blockIdx.x;
    int tid = threadIdx.x;
    float4 v4 = *(const float4*)&y[(size_t)row * 1024 + tid * 4];
    float v[4] = {v4.x, v4.y, v4.z, v4.w};
    float s = v[0] + v[1] + v[2] + v[3];
    float s2 = v[0]*v[0] + v[1]*v[1] + v[2]*v[2] + v[3]*v[3];
    #pragma unroll
    for (int off = 1; off < 64; off <<= 1) {
        s += __shfl_xor(s, off);
        s2 += __shfl_xor(s2, off);
    }
    __shared__ float red[8];
    int wave = tid >> 6, lane = tid & 63;
    if (lane == 0) { red[wave] = s; red[4 + wave] = s2; }
    __syncthreads();
    s = red[0] + red[1] + red[2] + red[3];
    s2 = red[4] + red[5] + red[6] + red[7];
    float mu = s * (1.f / 1024.f);
    float var = s2 * (1.f / 1024.f) - mu * mu;
    float rsq = rsqrtf(var + 1e-5f);
    float4 o4;
    float* o = (float*)&o4;
    #pragma unroll
    for (int e = 0; e < 4; e++) {
        int n = tid * 4 + e;
        o[e] = (v[e] - mu) * rsq * gamma[n] + beta[n];
    }
    *(float4*)&y[(size_t)row * 1024 + tid * 4] = o4;
}

extern "C" void kernel_launch(void* const* d_in, const int* in_sizes, int n_in,
                              void* d_out, int out_size, void* d_ws, size_t ws_size,
                              hipStream_t stream) {
    const float* x     = (const float*)d_in[0];
    const float* Wq    = (const float*)d_in[1];
    const float* bq    = (const float*)d_in[2];
    const float* Wk    = (const float*)d_in[3];
    const float* bk    = (const float*)d_in[4];
    const float* Wv    = (const float*)d_in[5];
    const float* bv    = (const float*)d_in[6];
    const float* Wg    = (const float*)d_in[7];
    const float* bg    = (const float*)d_in[8];
    const float* gamma = (const float*)d_in[9];
    const float* beta  = (const float*)d_in[10];
    float* out = (float*)d_out;   // reference output is fp32

    char* w = (char*)d_ws;
    const size_t MB = 1024 * 1024;
    short* xb  = (short*)(w + 0 * MB);    // [4096][1024] bf16
    short* Qb  = (short*)(w + 8 * MB);    // pre-scaled by QSCALE
    short* Kb  = (short*)(w + 16 * MB);
    short* Vb  = (short*)(w + 24 * MB);
    short* WT  = (short*)(w + 32 * MB);   // [3072][1024] bf16 (Wq^T|Wk^T|Wv^T)
    short* WgT = (short*)(w + 38 * MB);   // [1024][2048] bf16
    short* fb  = (short*)(w + 42 * MB);   // flowed bf16 [4096][1024]
    short* VT  = (short*)(w + 50 * MB);   // V^T per head [b*16+h][64 dv][2048 s]

    cvt_kernel<<<4096, 256, 0, stream>>>(x, xb, 4096 * 1024 / 4);
    dim3 tb(32, 8);
    transpose_bf16<<<dim3(32, 32), tb, 0, stream>>>(Wq, WT, 1024, 1024);
    transpose_bf16<<<dim3(32, 32), tb, 0, stream>>>(Wk, WT + 1024 * 1024, 1024, 1024);
    transpose_bf16<<<dim3(32, 32), tb, 0, stream>>>(Wv, WT + 2 * 1024 * 1024, 1024, 1024);
    transpose_bf16<<<dim3(32, 64), tb, 0, stream>>>(Wg, WgT, 2048, 1024);
    gemm_qkv<<<dim3(32, 24), 256, 0, stream>>>(xb, WT, bq, bk, bv, Qb, Kb, Vb);
    vtrans_kernel<<<dim3(64, 2, 32), tb, 0, stream>>>(Vb, VT);
    attn_kernel<<<512, 256, 0, stream>>>(Qb, Kb, VT, fb);
    gemm_gate<<<dim3(32, 8), 256, 0, stream>>>(xb, fb, WgT, bg, x, out);
    ln_kernel<<<4096, 256, 0, stream>>>(out, gamma, beta);
}

// Round 13
// 210.854 us; speedup vs baseline: 1.2429x; 1.2429x over previous
//
#include <hip/hip_runtime.h>
#include <hip/hip_bf16.h>

#define S_LEN 2048
#define NHEAD 16
#define HDIM 64
#define HID 1024

typedef __attribute__((ext_vector_type(8))) short bf16x8;
typedef __attribute__((ext_vector_type(4))) float f32x4;
typedef __attribute__((ext_vector_type(16))) float f32x16;
typedef __attribute__((ext_vector_type(4))) unsigned int u32x4;

__device__ __forceinline__ unsigned short f2bf(float x) {
    unsigned int u = __builtin_bit_cast(unsigned int, x);
    u = (u + 0x7fffu + ((u >> 16) & 1u)) >> 16;
    return (unsigned short)u;
}
__device__ __forceinline__ float bf2f(unsigned short s) {
    unsigned int u = ((unsigned int)s) << 16;
    return __builtin_bit_cast(float, u);
}
__device__ __forceinline__ unsigned cvtpk_bf16(float lo, float hi) {
    unsigned r;
    asm("v_cvt_pk_bf16_f32 %0, %1, %2" : "=v"(r) : "v"(lo), "v"(hi));
    return r;
}
__device__ __forceinline__ void gload16(const short* g, short* l) {
    __builtin_amdgcn_global_load_lds(
        (const __attribute__((address_space(1))) unsigned int*)g,
        (__attribute__((address_space(3))) unsigned int*)l, 16, 0, 0);
}
__device__ __forceinline__ bf16x8 negbf8(bf16x8 v) {
    u32x4 u = __builtin_bit_cast(u32x4, v);
    #pragma unroll
    for (int e = 0; e < 4; e++) u[e] ^= 0x80008000u;
    return __builtin_bit_cast(bf16x8, u);
}

// scale folded into Q: scores arrive as flow*log2(e) -> softmax via exp2
#define QSCALE 0.1803368801111168f   // 0.125 * log2(e)

// ---------------- prep: f32 -> bf16 convert (vectorized) ----------------
__global__ void cvt_kernel(const float* __restrict__ src, short* __restrict__ dst, int n4) {
    int i = blockIdx.x * blockDim.x + threadIdx.x;
    if (i < n4) {
        float4 v = reinterpret_cast<const float4*>(src)[i];
        short4 o;
        o.x = (short)f2bf(v.x); o.y = (short)f2bf(v.y);
        o.z = (short)f2bf(v.z); o.w = (short)f2bf(v.w);
        reinterpret_cast<short4*>(dst)[i] = o;
    }
}

// ------------- prep: tiled transpose f32 [R][C] -> bf16 [C][R] ----------
__global__ void transpose_bf16(const float* __restrict__ src, short* __restrict__ dst,
                               int R, int C) {
    __shared__ float tile[32][33];
    int bx = blockIdx.x * 32;
    int by = blockIdx.y * 32;
    int tx = threadIdx.x, ty = threadIdx.y;  // 32 x 8
    #pragma unroll
    for (int i = ty; i < 32; i += 8)
        tile[i][tx] = src[(size_t)(by + i) * C + bx + tx];
    __syncthreads();
    #pragma unroll
    for (int i = ty; i < 32; i += 8)
        dst[(size_t)(bx + i) * R + by + tx] = (short)f2bf(tile[tx][i]);
}

// ----- per-head V transpose: Vb[b*2048+s][h*64+dv] -> VT[(b*16+h)*64+dv][s]
__global__ void vtrans_kernel(const short* __restrict__ Vb, short* __restrict__ VT) {
    __shared__ short tile[32][34];
    int s0 = blockIdx.x * 32;
    int dv0 = blockIdx.y * 32;
    int bh = blockIdx.z;
    int b = bh >> 4, h = bh & 15;
    int tx = threadIdx.x, ty = threadIdx.y;  // 32 x 8
    #pragma unroll
    for (int i = ty; i < 32; i += 8)
        tile[i][tx] = Vb[(size_t)(b * S_LEN + s0 + i) * HID + h * HDIM + dv0 + tx];
    __syncthreads();
    #pragma unroll
    for (int i = ty; i < 32; i += 8)
        VT[(size_t)(bh * HDIM + dv0 + i) * S_LEN + s0 + tx] = tile[tx][i];
}

// ---------------- QKV GEMM: [4096,1024] @ [1024,3072] -------------------
__global__ __launch_bounds__(256, 2)
void gemm_qkv(const short* __restrict__ xb, const short* __restrict__ WT,
              const float* __restrict__ bq, const float* __restrict__ bk,
              const float* __restrict__ bv,
              short* __restrict__ Qb, short* __restrict__ Kb, short* __restrict__ Vb) {
    __shared__ short Al[128 * 32];
    __shared__ short Bl[128 * 32];
    int mb = blockIdx.x, nb = blockIdx.y;
    int tid = threadIdx.x;
    int wave = tid >> 6, lane = tid & 63;
    int wm = wave >> 1, wn = wave & 1;
    int lr = lane & 15, lg = lane >> 4;

    int r = tid >> 2;
    int c = tid & 3;
    int sc = (c ^ (r & 3)) * 8;
    int dst0 = tid * 8;
    int dst1 = (tid + 256) * 8;
    const short* a0 = xb + (size_t)(mb * 128 + r) * 1024 + sc;
    const short* a1 = a0 + (size_t)64 * 1024;
    const short* b0 = WT + (size_t)(nb * 128 + r) * 1024 + sc;
    const short* b1 = b0 + (size_t)64 * 1024;
    int fsw = (lg ^ (lr & 3)) * 8;

    f32x4 acc[4][4] = {};

    for (int ks = 0; ks < 32; ++ks) {
        __syncthreads();
        gload16(a0 + ks * 32, &Al[dst0]);
        gload16(a1 + ks * 32, &Al[dst1]);
        gload16(b0 + ks * 32, &Bl[dst0]);
        gload16(b1 + ks * 32, &Bl[dst1]);
        __syncthreads();
        bf16x8 af[4], bfr[4];
        #pragma unroll
        for (int t = 0; t < 4; t++)
            af[t] = *(bf16x8*)&Al[(wm * 64 + t * 16 + lr) * 32 + fsw];
        #pragma unroll
        for (int t = 0; t < 4; t++)
            bfr[t] = *(bf16x8*)&Bl[(wn * 64 + t * 16 + lr) * 32 + fsw];
        #pragma unroll
        for (int i = 0; i < 4; i++)
            #pragma unroll
            for (int jn = 0; jn < 4; jn++)
                acc[i][jn] = __builtin_amdgcn_mfma_f32_16x16x32_bf16(af[i], bfr[jn], acc[i][jn], 0, 0, 0);
    }

    #pragma unroll
    for (int jn = 0; jn < 4; jn++) {
        int n = nb * 128 + wn * 64 + jn * 16 + lr;
        int which = n >> 10;
        int n1 = n & 1023;
        const float* bias = (which == 0) ? bq : (which == 1) ? bk : bv;
        short* out = (which == 0) ? Qb : (which == 1) ? Kb : Vb;
        float scale = (which == 0) ? QSCALE : 1.0f;
        float bv_ = bias[n1];
        #pragma unroll
        for (int i = 0; i < 4; i++) {
            #pragma unroll
            for (int j = 0; j < 4; j++) {
                int mm = mb * 128 + wm * 64 + i * 16 + lg * 4 + j;
                out[(size_t)mm * 1024 + n1] = (short)f2bf((acc[i][jn][j] + bv_) * scale);
            }
        }
    }
}

// ---------------- flash attention with antisymmetric flow ---------------
// 32x32x16 MFMA form: 2 waves/block, each wave owns 32 q-rows fully.
// S^T[key][q] = mfma(A=K_tile, B=Q_wave) + mfma(A=Q_tile, B=-K_wave);
// lane holds col q = lane&31. P stays IN REGISTERS: cvt_pk pairs +
// __shfl_xor(.,32) + compile-time selects assemble PV A-frags (no P LDS).
// LDS per block: 24 KB; grid 1024 = 4 blocks/CU.
__global__ __launch_bounds__(128, 2)
void attn_kernel(const short* __restrict__ Qb, const short* __restrict__ Kb,
                 const short* __restrict__ VT, short* __restrict__ Fb) {
    __shared__ short Kt[64 * 64];
    __shared__ short Qt[64 * 64];
    __shared__ short Vt[64 * 64];

    int bid = blockIdx.x;
    int qb = bid & 31;               // 64-q block
    int bh = bid >> 5;
    int b = bh >> 4, h = bh & 15;
    int tid = threadIdx.x;
    int w = tid >> 6, l = tid & 63;
    int lq = l & 31, hi = l >> 5;

    // wave-side B-frags: Q and -K rows of wave's 32 q, k-slices s*16+hi*8
    size_t qrow = (size_t)(b * S_LEN + qb * 64 + w * 32 + lq) * HID + h * HDIM;
    bf16x8 Qf[4], nKf[4];
    #pragma unroll
    for (int s = 0; s < 4; s++) {
        Qf[s]  = *(const bf16x8*)(Qb + qrow + s * 16 + hi * 8);
        nKf[s] = negbf8(*(const bf16x8*)(Kb + qrow + s * 16 + hi * 8));
    }

    // staging: 24KB/tile, 12 gload16/thread. Region R (1KB) lane-linear dest;
    // source chunk XOR-swizzled so swizzled reads see linear data (rule #21).
    int roff[4], vroff[4], dsto[4];
    #pragma unroll
    for (int j = 0; j < 4; j++) {
        int R = w * 4 + j;
        int r = R * 8 + (l >> 3);
        int c = l & 7;
        int sw = (c ^ (r & 7)) * 8;
        roff[j] = r * HID + sw;
        vroff[j] = r * S_LEN + sw;
        dsto[j] = R * 512 + l * 8;
    }
    const short* kbase = Kb + (size_t)b * S_LEN * HID + h * HDIM;
    const short* qbase = Qb + (size_t)b * S_LEN * HID + h * HDIM;
    const short* vbase = VT + (size_t)bh * HDIM * S_LEN;

    f32x16 O0 = {}, O1 = {};         // dv blocks 0-31, 32-63
    float m = -1e30f, lsum = 0.f;    // per-lane state for q = lq (log2 domain)

    for (int kt = 0; kt < 32; ++kt) {
        __syncthreads();
        #pragma unroll
        for (int j = 0; j < 4; j++) {
            gload16(kbase + (size_t)kt * 64 * HID + roff[j], &Kt[dsto[j]]);
            gload16(qbase + (size_t)kt * 64 * HID + roff[j], &Qt[dsto[j]]);
            gload16(vbase + kt * 64 + vroff[j], &Vt[dsto[j]]);
        }
        __syncthreads();

        // S^T: two 32-key blocks, K(dot)=64 in 4 slices
        f32x16 S0 = {}, S1 = {};
        __builtin_amdgcn_s_setprio(1);
        #pragma unroll
        for (int s = 0; s < 4; s++) {
            int ch = ((2 * s + hi) ^ (lq & 7)) * 8;
            bf16x8 kf0 = *(bf16x8*)&Kt[lq * 64 + ch];
            bf16x8 qf0 = *(bf16x8*)&Qt[lq * 64 + ch];
            bf16x8 kf1 = *(bf16x8*)&Kt[(32 + lq) * 64 + ch];
            bf16x8 qf1 = *(bf16x8*)&Qt[(32 + lq) * 64 + ch];
            S0 = __builtin_amdgcn_mfma_f32_32x32x16_bf16(kf0, Qf[s], S0, 0, 0, 0);
            S0 = __builtin_amdgcn_mfma_f32_32x32x16_bf16(qf0, nKf[s], S0, 0, 0, 0);
            S1 = __builtin_amdgcn_mfma_f32_32x32x16_bf16(kf1, Qf[s], S1, 0, 0, 0);
            S1 = __builtin_amdgcn_mfma_f32_32x32x16_bf16(qf1, nKf[s], S1, 0, 0, 0);
        }
        __builtin_amdgcn_s_setprio(0);

        // row max over this lane's 32 key-values + other half via xor32
        float pm = -1e30f;
        #pragma unroll
        for (int g = 0; g < 16; g++) pm = fmaxf(pm, fmaxf(S0[g], S1[g]));
        pm = fmaxf(pm, __shfl_xor(pm, 32));

        // defer-max (T13)
        if (__any(pm > m + 8.f)) {
            float mn = fmaxf(m, pm);
            float al = exp2f(m - mn);
            m = mn; lsum *= al;
            #pragma unroll
            for (int g = 0; g < 16; g++) {
                float a = __shfl(al, (g & 3) + 8 * (g >> 2) + 4 * hi);
                O0[g] *= a; O1[g] *= a;
            }
        }

        // P = exp2(S-m) -> packed bf16 dwords (key pairs per C/D row map)
        unsigned pd0[8], pd1[8];
        float rs = 0.f;
        #pragma unroll
        for (int g = 0; g < 8; g++) {
            float a0 = exp2f(S0[2 * g] - m), a1 = exp2f(S0[2 * g + 1] - m);
            float b0 = exp2f(S1[2 * g] - m), b1 = exp2f(S1[2 * g + 1] - m);
            rs += (a0 + a1) + (b0 + b1);
            pd0[g] = cvtpk_bf16(a0, a1);
            pd1[g] = cvtpk_bf16(b0, b1);
        }
        rs += __shfl_xor(rs, 32);
        lsum += rs;

        // PV: A-frags via shfl_xor(32) + selects (verified key map).
        // Lane (lq,hi) needs keys ks*16 + hi*8 + 0..7 as 4 ascending dwords.
        __builtin_amdgcn_s_setprio(1);
        #pragma unroll
        for (int ks = 0; ks < 4; ks++) {
            int j0 = (ks & 1) * 4;
            unsigned p0 = (ks < 2) ? pd0[j0 + 0] : pd1[j0 + 0];
            unsigned p1 = (ks < 2) ? pd0[j0 + 1] : pd1[j0 + 1];
            unsigned p2 = (ks < 2) ? pd0[j0 + 2] : pd1[j0 + 2];
            unsigned p3 = (ks < 2) ? pd0[j0 + 3] : pd1[j0 + 3];
            unsigned x0 = (unsigned)__shfl_xor((int)p0, 32);
            unsigned x1 = (unsigned)__shfl_xor((int)p1, 32);
            unsigned x2 = (unsigned)__shfl_xor((int)p2, 32);
            unsigned x3 = (unsigned)__shfl_xor((int)p3, 32);
            u32x4 fd;
            fd[0] = hi ? x2 : p0;
            fd[1] = hi ? x3 : p1;
            fd[2] = hi ? p2 : x0;
            fd[3] = hi ? p3 : x1;
            bf16x8 pf = __builtin_bit_cast(bf16x8, fd);
            int ch = ((2 * ks + hi) ^ (lq & 7)) * 8;
            bf16x8 v0 = *(bf16x8*)&Vt[lq * 64 + ch];
            bf16x8 v1 = *(bf16x8*)&Vt[(32 + lq) * 64 + ch];
            O0 = __builtin_amdgcn_mfma_f32_32x32x16_bf16(pf, v0, O0, 0, 0, 0);
            O1 = __builtin_amdgcn_mfma_f32_32x32x16_bf16(pf, v1, O1, 0, 0, 0);
        }
        __builtin_amdgcn_s_setprio(0);
    }

    float linv = 1.f / lsum;
    #pragma unroll
    for (int g = 0; g < 16; g++) {
        int ql = (g & 3) + 8 * (g >> 2) + 4 * hi;
        float li = __shfl(linv, ql);
        int qg = qb * 64 + w * 32 + ql;
        size_t base = (size_t)(b * S_LEN + qg) * HID + h * HDIM;
        Fb[base + lq]      = (short)f2bf(O0[g] * li);
        Fb[base + 32 + lq] = (short)f2bf(O1[g] * li);
    }
}

// ------- gate GEMM (K=2048 over [xb | flowed]) + sigmoid + residual -----
__global__ __launch_bounds__(256, 2)
void gemm_gate(const short* __restrict__ xb, const short* __restrict__ fb,
               const short* __restrict__ WgT, const float* __restrict__ bg,
               const float* __restrict__ x, float* __restrict__ y) {
    __shared__ short Al[128 * 32];
    __shared__ short Bl[128 * 32];
    int mb = blockIdx.x, nb = blockIdx.y;
    int tid = threadIdx.x;
    int wave = tid >> 6, lane = tid & 63;
    int wm = wave >> 1, wn = wave & 1;
    int lr = lane & 15, lg = lane >> 4;

    int r = tid >> 2;
    int c = tid & 3;
    int sc = (c ^ (r & 3)) * 8;
    int dst0 = tid * 8;
    int dst1 = (tid + 256) * 8;
    size_t arow0 = (size_t)(mb * 128 + r) * 1024 + sc;
    size_t arow1 = arow0 + (size_t)64 * 1024;
    const short* b0 = WgT + (size_t)(nb * 128 + r) * 2048 + sc;
    const short* b1 = b0 + (size_t)64 * 2048;
    int fsw = (lg ^ (lr & 3)) * 8;

    f32x4 acc[4][4] = {};

    for (int ks = 0; ks < 64; ++ks) {
        int kg = ks * 32;
        const short* A = (kg < 1024) ? (xb + kg) : (fb + (kg - 1024));
        __syncthreads();
        gload16(A + arow0, &Al[dst0]);
        gload16(A + arow1, &Al[dst1]);
        gload16(b0 + kg, &Bl[dst0]);
        gload16(b1 + kg, &Bl[dst1]);
        __syncthreads();
        bf16x8 af[4], bfr[4];
        #pragma unroll
        for (int t = 0; t < 4; t++)
            af[t] = *(bf16x8*)&Al[(wm * 64 + t * 16 + lr) * 32 + fsw];
        #pragma unroll
        for (int t = 0; t < 4; t++)
            bfr[t] = *(bf16x8*)&Bl[(wn * 64 + t * 16 + lr) * 32 + fsw];
        #pragma unroll
        for (int i = 0; i < 4; i++)
            #pragma unroll
            for (int jn = 0; jn < 4; jn++)
                acc[i][jn] = __builtin_amdgcn_mfma_f32_16x16x32_bf16(af[i], bfr[jn], acc[i][jn], 0, 0, 0);
    }

    #pragma unroll
    for (int jn = 0; jn < 4; jn++) {
        int n = nb * 128 + wn * 64 + jn * 16 + lr;
        float bgv = bg[n];
        #pragma unroll
        for (int i = 0; i < 4; i++) {
            #pragma unroll
            for (int j = 0; j < 4; j++) {
                int mm = mb * 128 + wm * 64 + i * 16 + lg * 4 + j;
                size_t idx = (size_t)mm * 1024 + n;
                float z = acc[i][jn][j] + bgv;
                float gate = 1.f / (1.f + __expf(-z));
                float fv = bf2f((unsigned short)fb[idx]);
                y[idx] = x[idx] + gate * fv;
            }
        }
    }
}

// ---------------- row LayerNorm in place (fp32 -> fp32) ----------------
__global__ __launch_bounds__(256)
void ln_kernel(float* __restrict__ y, const float* __restrict__ gamma,
               const float* __restrict__ beta) {
    int row = blockIdx.x;
    int tid = threadIdx.x;
    float4 v4 = *(const float4*)&y[(size_t)row * 1024 + tid * 4];
    float v[4] = {v4.x, v4.y, v4.z, v4.w};
    float s = v[0] + v[1] + v[2] + v[3];
    float s2 = v[0]*v[0] + v[1]*v[1] + v[2]*v[2] + v[3]*v[3];
    #pragma unroll
    for (int off = 1; off < 64; off <<= 1) {
        s += __shfl_xor(s, off);
        s2 += __shfl_xor(s2, off);
    }
    __shared__ float red[8];
    int wave = tid >> 6, lane = tid & 63;
    if (lane == 0) { red[wave] = s; red[4 + wave] = s2; }
    __syncthreads();
    s = red[0] + red[1] + red[2] + red[3];
    s2 = red[4] + red[5] + red[6] + red[7];
    float mu = s * (1.f / 1024.f);
    float var = s2 * (1.f / 1024.f) - mu * mu;
    float rsq = rsqrtf(var + 1e-5f);
    float4 o4;
    float* o = (float*)&o4;
    #pragma unroll
    for (int e = 0; e < 4; e++) {
        int n = tid * 4 + e;
        o[e] = (v[e] - mu) * rsq * gamma[n] + beta[n];
    }
    *(float4*)&y[(size_t)row * 1024 + tid * 4] = o4;
}

extern "C" void kernel_launch(void* const* d_in, const int* in_sizes, int n_in,
                              void* d_out, int out_size, void* d_ws, size_t ws_size,
                              hipStream_t stream) {
    const float* x     = (const float*)d_in[0];
    const float* Wq    = (const float*)d_in[1];
    const float* bq    = (const float*)d_in[2];
    const float* Wk    = (const float*)d_in[3];
    const float* bk    = (const float*)d_in[4];
    const float* Wv    = (const float*)d_in[5];
    const float* bv    = (const float*)d_in[6];
    const float* Wg    = (const float*)d_in[7];
    const float* bg    = (const float*)d_in[8];
    const float* gamma = (const float*)d_in[9];
    const float* beta  = (const float*)d_in[10];
    float* out = (float*)d_out;   // reference output is fp32

    char* w = (char*)d_ws;
    const size_t MB = 1024 * 1024;
    short* xb  = (short*)(w + 0 * MB);    // [4096][1024] bf16
    short* Qb  = (short*)(w + 8 * MB);    // pre-scaled by QSCALE
    short* Kb  = (short*)(w + 16 * MB);
    short* Vb  = (short*)(w + 24 * MB);
    short* WT  = (short*)(w + 32 * MB);   // [3072][1024] bf16 (Wq^T|Wk^T|Wv^T)
    short* WgT = (short*)(w + 38 * MB);   // [1024][2048] bf16
    short* fb  = (short*)(w + 42 * MB);   // flowed bf16 [4096][1024]
    short* VT  = (short*)(w + 50 * MB);   // V^T per head [b*16+h][64 dv][2048 s]

    cvt_kernel<<<4096, 256, 0, stream>>>(x, xb, 4096 * 1024 / 4);
    dim3 tb(32, 8);
    transpose_bf16<<<dim3(32, 32), tb, 0, stream>>>(Wq, WT, 1024, 1024);
    transpose_bf16<<<dim3(32, 32), tb, 0, stream>>>(Wk, WT + 1024 * 1024, 1024, 1024);
    transpose_bf16<<<dim3(32, 32), tb, 0, stream>>>(Wv, WT + 2 * 1024 * 1024, 1024, 1024);
    transpose_bf16<<<dim3(32, 64), tb, 0, stream>>>(Wg, WgT, 2048, 1024);
    gemm_qkv<<<dim3(32, 24), 256, 0, stream>>>(xb, WT, bq, bk, bv, Qb, Kb, Vb);
    vtrans_kernel<<<dim3(64, 2, 32), tb, 0, stream>>>(Vb, VT);
    attn_kernel<<<1024, 128, 0, stream>>>(Qb, Kb, VT, fb);
    gemm_gate<<<dim3(32, 8), 256, 0, stream>>>(xb, fb, WgT, bg, x, out);
    ln_kernel<<<4096, 256, 0, stream>>>(out, gamma, beta);
}

// Round 14
// 189.304 us; speedup vs baseline: 1.3844x; 1.1138x over previous
//
#include <hip/hip_runtime.h>
#include <hip/hip_bf16.h>

#define S_LEN 2048
#define NHEAD 16
#define HDIM 64
#define HID 1024

typedef __attribute__((ext_vector_type(8))) short bf16x8;
typedef __attribute__((ext_vector_type(4))) float f32x4;
typedef __attribute__((ext_vector_type(4))) unsigned int u32x4;
typedef __attribute__((ext_vector_type(2))) unsigned int u32x2;

__device__ __forceinline__ unsigned short f2bf(float x) {
    unsigned int u = __builtin_bit_cast(unsigned int, x);
    u = (u + 0x7fffu + ((u >> 16) & 1u)) >> 16;
    return (unsigned short)u;
}
__device__ __forceinline__ float bf2f(unsigned short s) {
    unsigned int u = ((unsigned int)s) << 16;
    return __builtin_bit_cast(float, u);
}
__device__ __forceinline__ unsigned cvtpk_bf16(float lo, float hi) {
    unsigned r;
    asm("v_cvt_pk_bf16_f32 %0, %1, %2" : "=v"(r) : "v"(lo), "v"(hi));
    return r;
}
__device__ __forceinline__ void gload16(const short* g, short* l) {
    __builtin_amdgcn_global_load_lds(
        (const __attribute__((address_space(1))) unsigned int*)g,
        (__attribute__((address_space(3))) unsigned int*)l, 16, 0, 0);
}
__device__ __forceinline__ bf16x8 negbf8(bf16x8 v) {
    u32x4 u = __builtin_bit_cast(u32x4, v);
    #pragma unroll
    for (int e = 0; e < 4; e++) u[e] ^= 0x80008000u;
    return __builtin_bit_cast(bf16x8, u);
}

// scale folded into Q: scores arrive as flow*log2(e) -> softmax via exp2
#define QSCALE 0.1803368801111168f   // 0.125 * log2(e)

// ---------------- prep: f32 -> bf16 convert (vectorized) ----------------
__global__ void cvt_kernel(const float* __restrict__ src, short* __restrict__ dst, int n4) {
    int i = blockIdx.x * blockDim.x + threadIdx.x;
    if (i < n4) {
        float4 v = reinterpret_cast<const float4*>(src)[i];
        short4 o;
        o.x = (short)f2bf(v.x); o.y = (short)f2bf(v.y);
        o.z = (short)f2bf(v.z); o.w = (short)f2bf(v.w);
        reinterpret_cast<short4*>(dst)[i] = o;
    }
}

// ------------- prep: tiled transpose f32 [R][C] -> bf16 [C][R] ----------
__global__ void transpose_bf16(const float* __restrict__ src, short* __restrict__ dst,
                               int R, int C) {
    __shared__ float tile[32][33];
    int bx = blockIdx.x * 32;
    int by = blockIdx.y * 32;
    int tx = threadIdx.x, ty = threadIdx.y;  // 32 x 8
    #pragma unroll
    for (int i = ty; i < 32; i += 8)
        tile[i][tx] = src[(size_t)(by + i) * C + bx + tx];
    __syncthreads();
    #pragma unroll
    for (int i = ty; i < 32; i += 8)
        dst[(size_t)(bx + i) * R + by + tx] = (short)f2bf(tile[tx][i]);
}

// ----- per-head V transpose: Vb[b*2048+s][h*64+dv] -> VT[(b*16+h)*64+dv][s]
__global__ void vtrans_kernel(const short* __restrict__ Vb, short* __restrict__ VT) {
    __shared__ short tile[32][34];
    int s0 = blockIdx.x * 32;
    int dv0 = blockIdx.y * 32;
    int bh = blockIdx.z;
    int b = bh >> 4, h = bh & 15;
    int tx = threadIdx.x, ty = threadIdx.y;  // 32 x 8
    #pragma unroll
    for (int i = ty; i < 32; i += 8)
        tile[i][tx] = Vb[(size_t)(b * S_LEN + s0 + i) * HID + h * HDIM + dv0 + tx];
    __syncthreads();
    #pragma unroll
    for (int i = ty; i < 32; i += 8)
        VT[(size_t)(bh * HDIM + dv0 + i) * S_LEN + s0 + tx] = tile[tx][i];
}

// ---------------- QKV GEMM: [4096,1024] @ [1024,3072] -------------------
__global__ __launch_bounds__(256, 2)
void gemm_qkv(const short* __restrict__ xb, const short* __restrict__ WT,
              const float* __restrict__ bq, const float* __restrict__ bk,
              const float* __restrict__ bv,
              short* __restrict__ Qb, short* __restrict__ Kb, short* __restrict__ Vb) {
    __shared__ short Al[128 * 32];
    __shared__ short Bl[128 * 32];
    int mb = blockIdx.x, nb = blockIdx.y;
    int tid = threadIdx.x;
    int wave = tid >> 6, lane = tid & 63;
    int wm = wave >> 1, wn = wave & 1;
    int lr = lane & 15, lg = lane >> 4;

    int r = tid >> 2;
    int c = tid & 3;
    int sc = (c ^ (r & 3)) * 8;
    int dst0 = tid * 8;
    int dst1 = (tid + 256) * 8;
    const short* a0 = xb + (size_t)(mb * 128 + r) * 1024 + sc;
    const short* a1 = a0 + (size_t)64 * 1024;
    const short* b0 = WT + (size_t)(nb * 128 + r) * 1024 + sc;
    const short* b1 = b0 + (size_t)64 * 1024;
    int fsw = (lg ^ (lr & 3)) * 8;

    f32x4 acc[4][4] = {};

    for (int ks = 0; ks < 32; ++ks) {
        __syncthreads();
        gload16(a0 + ks * 32, &Al[dst0]);
        gload16(a1 + ks * 32, &Al[dst1]);
        gload16(b0 + ks * 32, &Bl[dst0]);
        gload16(b1 + ks * 32, &Bl[dst1]);
        __syncthreads();
        bf16x8 af[4], bfr[4];
        #pragma unroll
        for (int t = 0; t < 4; t++)
            af[t] = *(bf16x8*)&Al[(wm * 64 + t * 16 + lr) * 32 + fsw];
        #pragma unroll
        for (int t = 0; t < 4; t++)
            bfr[t] = *(bf16x8*)&Bl[(wn * 64 + t * 16 + lr) * 32 + fsw];
        #pragma unroll
        for (int i = 0; i < 4; i++)
            #pragma unroll
            for (int jn = 0; jn < 4; jn++)
                acc[i][jn] = __builtin_amdgcn_mfma_f32_16x16x32_bf16(af[i], bfr[jn], acc[i][jn], 0, 0, 0);
    }

    #pragma unroll
    for (int jn = 0; jn < 4; jn++) {
        int n = nb * 128 + wn * 64 + jn * 16 + lr;
        int which = n >> 10;
        int n1 = n & 1023;
        const float* bias = (which == 0) ? bq : (which == 1) ? bk : bv;
        short* out = (which == 0) ? Qb : (which == 1) ? Kb : Vb;
        float scale = (which == 0) ? QSCALE : 1.0f;
        float bv_ = bias[n1];
        #pragma unroll
        for (int i = 0; i < 4; i++) {
            #pragma unroll
            for (int j = 0; j < 4; j++) {
                int mm = mb * 128 + wm * 64 + i * 16 + lg * 4 + j;
                out[(size_t)mm * 1024 + n1] = (short)f2bf((acc[i][jn][j] + bv_) * scale);
            }
        }
    }
}

// ---------------- flash attention with antisymmetric flow ---------------
// r9 known-good: log2-domain scores (Q pre-scaled); wave-side Kf negated
// once; T2 XOR swizzle; T14 reg prefetch; Pl LDS P-path. 96 us measured.
__global__ __launch_bounds__(256, 4)
void attn_kernel(const short* __restrict__ Qb, const short* __restrict__ Kb,
                 const short* __restrict__ VT, short* __restrict__ Fb) {
    __shared__ short Kt[64 * 64];
    __shared__ short Qt[64 * 64];
    __shared__ short Vt[64 * 64];
    __shared__ short Pl[4][16 * 64];

    int bid = blockIdx.x;
    int qb = bid & 31;
    int bh = bid >> 5;
    int b = bh >> 4, h = bh & 15;
    int tid = threadIdx.x;
    int wave = tid >> 6, lane = tid & 63;
    int lr = lane & 15, lg = lane >> 4;

    size_t rowbase = ((size_t)(b * S_LEN + qb * 64 + wave * 16 + lr)) * HID + h * HDIM;
    bf16x8 Qf[2], Kf[2];
    #pragma unroll
    for (int cc = 0; cc < 2; cc++) {
        Qf[cc] = *(const bf16x8*)(Qb + rowbase + cc * 32 + lg * 8);
        Kf[cc] = negbf8(*(const bf16x8*)(Kb + rowbase + cc * 32 + lg * 8));
    }

    int r0 = tid >> 3;
    int c = tid & 7;
    int swz = (c ^ (r0 & 7)) * 8;
    int dst0 = r0 * 64 + swz;
    int dst1 = (r0 + 32) * 64 + swz;
    const short* kp = Kb + (size_t)(b * S_LEN + r0) * HID + h * HDIM + c * 8;
    const short* qp = Qb + (size_t)(b * S_LEN + r0) * HID + h * HDIM + c * 8;
    const short* vp = VT + (size_t)bh * HDIM * S_LEN + (size_t)r0 * S_LEN + c * 8;

    bf16x8 kv0 = *(const bf16x8*)kp;
    bf16x8 kv1 = *(const bf16x8*)(kp + 32 * HID);
    bf16x8 qv0 = *(const bf16x8*)qp;
    bf16x8 qv1 = *(const bf16x8*)(qp + 32 * HID);
    bf16x8 vv0 = *(const bf16x8*)vp;
    bf16x8 vv1 = *(const bf16x8*)(vp + 32 * S_LEN);
    kp += 64 * HID; qp += 64 * HID; vp += 64;

    f32x4 O[4] = {};
    float m = -1e30f, l = 0.f;

    for (int kt = 0; kt < 32; ++kt) {
        __syncthreads();
        *(bf16x8*)&Kt[dst0] = kv0;
        *(bf16x8*)&Kt[dst1] = kv1;
        *(bf16x8*)&Qt[dst0] = qv0;
        *(bf16x8*)&Qt[dst1] = qv1;
        *(bf16x8*)&Vt[dst0] = vv0;
        *(bf16x8*)&Vt[dst1] = vv1;
        __syncthreads();

        if (kt < 31) {
            kv0 = *(const bf16x8*)kp;
            kv1 = *(const bf16x8*)(kp + 32 * HID);
            qv0 = *(const bf16x8*)qp;
            qv1 = *(const bf16x8*)(qp + 32 * HID);
            vv0 = *(const bf16x8*)vp;
            vv1 = *(const bf16x8*)(vp + 32 * S_LEN);
            kp += 64 * HID; qp += 64 * HID; vp += 64;
        }

        f32x4 S[4] = {};
        __builtin_amdgcn_s_setprio(1);
        #pragma unroll
        for (int t = 0; t < 4; t++) {
            #pragma unroll
            for (int c2 = 0; c2 < 2; c2++) {
                int fo = (t * 16 + lr) * 64 + (((4 * c2 + lg) ^ (lr & 7)) * 8);
                bf16x8 kf = *(bf16x8*)&Kt[fo];
                bf16x8 qf = *(bf16x8*)&Qt[fo];
                S[t] = __builtin_amdgcn_mfma_f32_16x16x32_bf16(kf, Qf[c2], S[t], 0, 0, 0);
                S[t] = __builtin_amdgcn_mfma_f32_16x16x32_bf16(qf, Kf[c2], S[t], 0, 0, 0);
            }
        }
        __builtin_amdgcn_s_setprio(0);

        float pm = -1e30f;
        #pragma unroll
        for (int t = 0; t < 4; t++)
            #pragma unroll
            for (int j = 0; j < 4; j++) pm = fmaxf(pm, S[t][j]);
        pm = fmaxf(pm, __shfl_xor(pm, 16));
        pm = fmaxf(pm, __shfl_xor(pm, 32));

        if (__any(pm > m + 8.f)) {
            float mn = fmaxf(m, pm);
            float alpha = exp2f(m - mn);
            m = mn;
            l *= alpha;
            float a[4];
            #pragma unroll
            for (int j = 0; j < 4; j++) a[j] = __shfl(alpha, lg * 4 + j);
            #pragma unroll
            for (int dvt = 0; dvt < 4; dvt++)
                #pragma unroll
                for (int j = 0; j < 4; j++) O[dvt][j] *= a[j];
        }

        unsigned Pd[4][2];
        float rs = 0.f;
        #pragma unroll
        for (int t = 0; t < 4; t++) {
            float p0 = exp2f(S[t][0] - m);
            float p1 = exp2f(S[t][1] - m);
            float p2 = exp2f(S[t][2] - m);
            float p3 = exp2f(S[t][3] - m);
            rs += (p0 + p1) + (p2 + p3);
            Pd[t][0] = cvtpk_bf16(p0, p1);
            Pd[t][1] = cvtpk_bf16(p2, p3);
        }
        rs += __shfl_xor(rs, 16);
        rs += __shfl_xor(rs, 32);
        l += rs;
        #pragma unroll
        for (int t = 0; t < 4; t++) {
            u32x2 pw;
            pw[0] = Pd[t][0];
            pw[1] = Pd[t][1];
            int po = lr * 64 + (((2 * t + (lg >> 1)) ^ (lr & 7)) * 8) + (lg & 1) * 4;
            *(u32x2*)&Pl[wave][po] = pw;
        }

        __builtin_amdgcn_s_setprio(1);
        #pragma unroll
        for (int c2 = 0; c2 < 2; c2++) {
            bf16x8 pf = *(bf16x8*)&Pl[wave][lr * 64 + (((4 * c2 + lg) ^ (lr & 7)) * 8)];
            #pragma unroll
            for (int dvt = 0; dvt < 4; dvt++) {
                bf16x8 vf = *(bf16x8*)&Vt[(dvt * 16 + lr) * 64 + (((4 * c2 + lg) ^ (lr & 7)) * 8)];
                O[dvt] = __builtin_amdgcn_mfma_f32_16x16x32_bf16(pf, vf, O[dvt], 0, 0, 0);
            }
        }
        __builtin_amdgcn_s_setprio(0);
    }

    float linv = 1.f / l;
    float li[4];
    #pragma unroll
    for (int j = 0; j < 4; j++) li[j] = __shfl(linv, lg * 4 + j);
    #pragma unroll
    for (int dvt = 0; dvt < 4; dvt++) {
        #pragma unroll
        for (int j = 0; j < 4; j++) {
            int q = qb * 64 + wave * 16 + lg * 4 + j;
            int dv = dvt * 16 + lr;
            Fb[((size_t)(b * S_LEN + q)) * HID + h * HDIM + dv] =
                (short)f2bf(O[dvt][j] * li[j]);
        }
    }
}

// ------- gate GEMM (K=2048 over [xb | flowed]) + sigmoid + residual -----
// 64x64 tile, grid 64x16 = 1024 blocks = 4 blocks/CU (was 1/CU at 128x128:
// the occupancy pathology). 1 gload16/thread each for A and B per K-step.
__global__ __launch_bounds__(256, 4)
void gemm_gate(const short* __restrict__ xb, const short* __restrict__ fb,
               const short* __restrict__ WgT, const float* __restrict__ bg,
               const float* __restrict__ x, float* __restrict__ y) {
    __shared__ short Al[64 * 32];
    __shared__ short Bl[64 * 32];
    int mb = blockIdx.x, nb = blockIdx.y;
    int tid = threadIdx.x;
    int wave = tid >> 6, lane = tid & 63;
    int wm = wave >> 1, wn = wave & 1;
    int lr = lane & 15, lg = lane >> 4;

    int r = tid >> 2;                 // 0..63
    int c = tid & 3;
    int sc = (c ^ (r & 3)) * 8;
    int dst0 = tid * 8;
    size_t arow0 = (size_t)(mb * 64 + r) * 1024 + sc;
    const short* b0 = WgT + (size_t)(nb * 64 + r) * 2048 + sc;
    int fsw = (lg ^ (lr & 3)) * 8;

    f32x4 acc[2][2] = {};

    for (int ks = 0; ks < 64; ++ks) {
        int kg = ks * 32;
        const short* A = (kg < 1024) ? (xb + kg) : (fb + (kg - 1024));
        __syncthreads();
        gload16(A + arow0, &Al[dst0]);
        gload16(b0 + kg, &Bl[dst0]);
        __syncthreads();
        bf16x8 af[2], bfr[2];
        #pragma unroll
        for (int t = 0; t < 2; t++)
            af[t] = *(bf16x8*)&Al[(wm * 32 + t * 16 + lr) * 32 + fsw];
        #pragma unroll
        for (int t = 0; t < 2; t++)
            bfr[t] = *(bf16x8*)&Bl[(wn * 32 + t * 16 + lr) * 32 + fsw];
        #pragma unroll
        for (int i = 0; i < 2; i++)
            #pragma unroll
            for (int jn = 0; jn < 2; jn++)
                acc[i][jn] = __builtin_amdgcn_mfma_f32_16x16x32_bf16(af[i], bfr[jn], acc[i][jn], 0, 0, 0);
    }

    #pragma unroll
    for (int jn = 0; jn < 2; jn++) {
        int n = nb * 64 + wn * 32 + jn * 16 + lr;
        float bgv = bg[n];
        #pragma unroll
        for (int i = 0; i < 2; i++) {
            #pragma unroll
            for (int j = 0; j < 4; j++) {
                int mm = mb * 64 + wm * 32 + i * 16 + lg * 4 + j;
                size_t idx = (size_t)mm * 1024 + n;
                float z = acc[i][jn][j] + bgv;
                float gate = 1.f / (1.f + __expf(-z));
                float fv = bf2f((unsigned short)fb[idx]);
                y[idx] = x[idx] + gate * fv;
            }
        }
    }
}

// ---------------- row LayerNorm in place (fp32 -> fp32) ----------------
__global__ __launch_bounds__(256)
void ln_kernel(float* __restrict__ y, const float* __restrict__ gamma,
               const float* __restrict__ beta) {
    int row = blockIdx.x;
    int tid = threadIdx.x;
    float4 v4 = *(const float4*)&y[(size_t)row * 1024 + tid * 4];
    float v[4] = {v4.x, v4.y, v4.z, v4.w};
    float s = v[0] + v[1] + v[2] + v[3];
    float s2 = v[0]*v[0] + v[1]*v[1] + v[2]*v[2] + v[3]*v[3];
    #pragma unroll
    for (int off = 1; off < 64; off <<= 1) {
        s += __shfl_xor(s, off);
        s2 += __shfl_xor(s2, off);
    }
    __shared__ float red[8];
    int wave = tid >> 6, lane = tid & 63;
    if (lane == 0) { red[wave] = s; red[4 + wave] = s2; }
    __syncthreads();
    s = red[0] + red[1] + red[2] + red[3];
    s2 = red[4] + red[5] + red[6] + red[7];
    float mu = s * (1.f / 1024.f);
    float var = s2 * (1.f / 1024.f) - mu * mu;
    float rsq = rsqrtf(var + 1e-5f);
    float4 o4;
    float* o = (float*)&o4;
    #pragma unroll
    for (int e = 0; e < 4; e++) {
        int n = tid * 4 + e;
        o[e] = (v[e] - mu) * rsq * gamma[n] + beta[n];
    }
    *(float4*)&y[(size_t)row * 1024 + tid * 4] = o4;
}

extern "C" void kernel_launch(void* const* d_in, const int* in_sizes, int n_in,
                              void* d_out, int out_size, void* d_ws, size_t ws_size,
                              hipStream_t stream) {
    const float* x     = (const float*)d_in[0];
    const float* Wq    = (const float*)d_in[1];
    const float* bq    = (const float*)d_in[2];
    const float* Wk    = (const float*)d_in[3];
    const float* bk    = (const float*)d_in[4];
    const float* Wv    = (const float*)d_in[5];
    const float* bv    = (const float*)d_in[6];
    const float* Wg    = (const float*)d_in[7];
    const float* bg    = (const float*)d_in[8];
    const float* gamma = (const float*)d_in[9];
    const float* beta  = (const float*)d_in[10];
    float* out = (float*)d_out;   // reference output is fp32

    char* w = (char*)d_ws;
    const size_t MB = 1024 * 1024;
    short* xb  = (short*)(w + 0 * MB);    // [4096][1024] bf16
    short* Qb  = (short*)(w + 8 * MB);    // pre-scaled by QSCALE
    short* Kb  = (short*)(w + 16 * MB);
    short* Vb  = (short*)(w + 24 * MB);
    short* WT  = (short*)(w + 32 * MB);   // [3072][1024] bf16 (Wq^T|Wk^T|Wv^T)
    short* WgT = (short*)(w + 38 * MB);   // [1024][2048] bf16
    short* fb  = (short*)(w + 42 * MB);   // flowed bf16 [4096][1024]
    short* VT  = (short*)(w + 50 * MB);   // V^T per head [b*16+h][64 dv][2048 s]

    cvt_kernel<<<4096, 256, 0, stream>>>(x, xb, 4096 * 1024 / 4);
    dim3 tb(32, 8);
    transpose_bf16<<<dim3(32, 32), tb, 0, stream>>>(Wq, WT, 1024, 1024);
    transpose_bf16<<<dim3(32, 32), tb, 0, stream>>>(Wk, WT + 1024 * 1024, 1024, 1024);
    transpose_bf16<<<dim3(32, 32), tb, 0, stream>>>(Wv, WT + 2 * 1024 * 1024, 1024, 1024);
    transpose_bf16<<<dim3(32, 64), tb, 0, stream>>>(Wg, WgT, 2048, 1024);
    gemm_qkv<<<dim3(32, 24), 256, 0, stream>>>(xb, WT, bq, bk, bv, Qb, Kb, Vb);
    vtrans_kernel<<<dim3(64, 2, 32), tb, 0, stream>>>(Vb, VT);
    attn_kernel<<<1024, 256, 0, stream>>>(Qb, Kb, VT, fb);
    gemm_gate<<<dim3(64, 16), 256, 0, stream>>>(xb, fb, WgT, bg, x, out);
    ln_kernel<<<4096, 256, 0, stream>>>(out, gamma, beta);
}